// Round 5
// baseline (671.601 us; speedup 1.0000x reference)
//
#include <hip/hip_runtime.h>

#define SEQ   2048
#define BATCH 4096
#define HD    32

// ---------------- fast device math ----------------
__device__ __forceinline__ float exp2_fast(float a) {
#if __has_builtin(__builtin_amdgcn_exp2f)
    return __builtin_amdgcn_exp2f(a);
#else
    return exp2f(a);
#endif
}

__device__ __forceinline__ float rcp_fast(float a) {
#if __has_builtin(__builtin_amdgcn_rcpf)
    return __builtin_amdgcn_rcpf(a);
#else
    return 1.0f / a;
#endif
}

// tanh(x) = sign(x) * (1 - e^{-2|x|}) / (1 + e^{-2|x|})
__device__ __forceinline__ float fast_tanh(float v) {
    float ax = fabsf(v);
    float e  = exp2_fast(ax * -2.8853900817779268f);
    float r  = (1.0f - e) * rcp_fast(1.0f + e);
    return copysignf(r, v);
}

// Single-instruction DPP mov (ctrl is a template param -> always ICE).
// bound_ctrl=true: invalid/out-of-range lanes read 0.
template <int CTRL>
__device__ __forceinline__ float dpp_movf(float v) {
#if __has_builtin(__builtin_amdgcn_mov_dpp)
    return __int_as_float(
        __builtin_amdgcn_mov_dpp(__float_as_int(v), CTRL, 0xF, 0xF, true));
#else
    return __int_as_float(
        __builtin_amdgcn_update_dpp(0, __float_as_int(v), CTRL, 0xF, 0xF, false));
#endif
}

// ---------------- kernel ----------------
// 32 lanes per batch element; lane s owns h row s (full 32-FMA dot per lane,
// no cross-lane reduce for z). h state in LDS; per step each lane reads the
// whole 32-float h vector as 8x ds_read_b128 BROADCASTS (2 distinct addrs per
// wave64 -> conflict-free) and writes 1 float (2-way across halves -> free).
// Out-projection: lag-1 DPP reduce (shr1,2,4,8 + row_bcast15) on the previous
// h register, scheduled inside the ds_read latency window.
// 512 thr/block x 256 blocks = 2048 waves = 2 waves/SIMD (latency hiding).
__global__ __launch_bounds__(512, 2) void rnn_elman_kernel(
    const float* __restrict__ x, const float* __restrict__ hidden,
    const float* __restrict__ W_ih, const float* __restrict__ b_ih,
    const float* __restrict__ W_hh, const float* __restrict__ b_hh,
    const float* __restrict__ W_fc, const float* __restrict__ b_fc,
    float* __restrict__ out)
{
    // 16 elements/block, slot stride 36 floats (144 B, 16B-aligned):
    // quad k of element eb sits at banks (4*eb + 4k)..+3 mod 32 -> the two
    // elements of a wave use disjoint bank quads; within an element all 32
    // lanes read the same address (broadcast).
    __shared__ float sh[16 * 36];

    const int tid = threadIdx.x;
    const int s   = tid & 31;               // h row owned by this lane
    const int eb  = tid >> 5;               // element within block (0..15)
    const int e   = blockIdx.x * 16 + eb;   // global batch element

    // ---- weights into registers ----
    float4 w[8];
    {
        const float4* Wr = reinterpret_cast<const float4*>(W_hh + s * HD);
        #pragma unroll
        for (int k = 0; k < 8; ++k) w[k] = Wr[k];
    }
    const float wih  = W_ih[s];
    const float bias = b_ih[s] + b_hh[s];
    const float wfc  = W_fc[s];
    const float bfc  = b_fc[0];

    // ---- LDS pointers (loop-invariant) ----
    float* slot = sh + eb * 36;
    float* wp   = slot + s;                                    // own h row
    const float4* qp = reinterpret_cast<const float4*>(slot);  // broadcast reads

    // ---- init h_0 ----
    float hprev = hidden[e * HD + s];
    *wp = hprev;
    __builtin_amdgcn_wave_barrier();

    // ---- x prefetch pipe (distance 4) ----
    float xq0 = x[0 * BATCH + e];
    float xq1 = x[1 * BATCH + e];
    float xq2 = x[2 * BATCH + e];
    float xq3 = x[3 * BATCH + e];

    #pragma unroll 4
    for (int t = 0; t < SEQ; ++t) {
        // ---- read full h_t vector (broadcast; written at end of prev iter) ----
        const float4 q0 = qp[0];
        const float4 q1 = qp[1];
        const float4 q2 = qp[2];
        const float4 q3 = qp[3];
        const float4 q4 = qp[4];
        const float4 q5 = qp[5];
        const float4 q6 = qp[6];
        const float4 q7 = qp[7];

        // ---- latency-cover window: lag-1 out-projection on hprev (= h_t) ----
        // reduce p over the 32 lanes of the element: shr 1,2,4,8 within each
        // 16-row, then row_bcast15 carries row-low's sum into row-high;
        // lane 31 of the element holds the full sum.
        {
            float p = hprev * wfc;
            p += dpp_movf<0x111>(p);   // row_shr:1
            p += dpp_movf<0x112>(p);   // row_shr:2
            p += dpp_movf<0x114>(p);   // row_shr:4
            p += dpp_movf<0x118>(p);   // row_shr:8  -> lane15/31 have 16-sums
            p += dpp_movf<0x142>(p);   // row_bcast15 -> lanes16..31 += lane15
            if ((t != 0) && (s == 31)) out[(t - 1) * BATCH + e] = p + bfc;
        }

        // ---- x pipe shuffle + refill ----
        const float xv = xq0;
        xq0 = xq1; xq1 = xq2; xq2 = xq3;
        {
            int tt = t + 4; tt = tt < SEQ - 1 ? tt : SEQ - 1;
            xq3 = x[tt * BATCH + e];
        }

        // ---- full-row matvec: 4 independent chains over the 8 quads ----
        float a0 = fmaf(xv, wih, bias);
        float a1 = 0.f, a2 = 0.f, a3 = 0.f;
        #define MV_Q(q, k)                                \
            a0 = fmaf(w[k].x, (q).x, a0);                 \
            a1 = fmaf(w[k].y, (q).y, a1);                 \
            a2 = fmaf(w[k].z, (q).z, a2);                 \
            a3 = fmaf(w[k].w, (q).w, a3);
        MV_Q(q0, 0) MV_Q(q1, 1) MV_Q(q2, 2) MV_Q(q3, 3)
        MV_Q(q4, 4) MV_Q(q5, 5) MV_Q(q6, 6) MV_Q(q7, 7)
        #undef MV_Q
        const float z = (a0 + a1) + (a2 + a3);

        const float h = fast_tanh(z);

        // ---- publish own row for next step ----
        *wp  = h;
        hprev = h;
        __builtin_amdgcn_wave_barrier();
    }

    // ---- epilogue: out for the final step ----
    {
        float p = hprev * wfc;
        p += dpp_movf<0x111>(p);
        p += dpp_movf<0x112>(p);
        p += dpp_movf<0x114>(p);
        p += dpp_movf<0x118>(p);
        p += dpp_movf<0x142>(p);
        if (s == 31) out[(SEQ - 1) * BATCH + e] = p + bfc;
    }
}

// ---------------- launch ----------------
extern "C" void kernel_launch(void* const* d_in, const int* in_sizes, int n_in,
                              void* d_out, int out_size, void* d_ws, size_t ws_size,
                              hipStream_t stream) {
    const float* x    = (const float*)d_in[0];
    const float* hid  = (const float*)d_in[1];
    const float* W_ih = (const float*)d_in[2];
    const float* b_ih = (const float*)d_in[3];
    const float* W_hh = (const float*)d_in[4];
    const float* b_hh = (const float*)d_in[5];
    const float* W_fc = (const float*)d_in[6];
    const float* b_fc = (const float*)d_in[7];
    float* out = (float*)d_out;

    dim3 grid(BATCH / 16);   // 256 blocks -> 1 block/CU
    dim3 block(512);         // 16 elements x 32 lanes, 8 waves -> 2 waves/SIMD
    rnn_elman_kernel<<<grid, block, 0, stream>>>(x, hid, W_ih, b_ih, W_hh, b_hh,
                                                 W_fc, b_fc, out);
}